// Round 1
// baseline (31.249 us; speedup 1.0000x reference)
//
#include <hip/hip_runtime.h>

// 4-qubit circuit, B=2^20 samples.
// Key identity: psi_final = U * e(x), where
//   e(x)[16]  = real product state from embedding RY(pi*x_w) on |0000>
//   U[16][16] = fixed complex unitary from the variational layers (weights only)
// <Z_w> = sum_j sign_w(j) * |psi_j|^2,  sign_w(j) = +1 if bit_w(j)==0 else -1.
// Wire w corresponds to bit (3-w) of the flat index j (wire 0 = MSB).

__device__ float g_Ur[256];
__device__ float g_Ui[256];

// ---------------- prep: build U from weights (one wave; lane k = column k) ----
__global__ __launch_bounds__(64) void qc_prep(const float* __restrict__ w) {
    const int k = threadIdx.x;
    if (k >= 16) return;

    float vr[16], vi[16];
#pragma unroll
    for (int j = 0; j < 16; ++j) { vr[j] = (j == k) ? 1.f : 0.f; vi[j] = 0.f; }

#pragma unroll
    for (int d = 0; d < 2; ++d) {
        // CNOT ring: (0,1),(1,2),(2,3),(3,0)  [control,target]
#pragma unroll
        for (int p = 0; p < 4; ++p) {
            const int cw = p;               // control wire
            const int tw = (p + 1) & 3;     // target wire
            const int mc = 8 >> cw;
            const int mt = 8 >> tw;
#pragma unroll
            for (int j = 0; j < 16; ++j) {
                if ((j & mc) && !(j & mt)) {
                    const int j2 = j | mt;
                    float tr = vr[j], ti = vi[j];
                    vr[j] = vr[j2];  vi[j] = vi[j2];
                    vr[j2] = tr;     vi[j2] = ti;
                }
            }
        }
        // per-wire RY(w[d][i][0]) then RZ(w[d][i][1])
#pragma unroll
        for (int i = 0; i < 4; ++i) {
            const int mw = 8 >> i;
            const float th = w[(d * 4 + i) * 2 + 0];
            const float c = cosf(0.5f * th), s = sinf(0.5f * th);
#pragma unroll
            for (int j = 0; j < 16; ++j) {
                if (!(j & mw)) {
                    const int j1 = j | mw;
                    float ar = vr[j], ai = vi[j], br = vr[j1], bi = vi[j1];
                    vr[j]  = c * ar - s * br;   vi[j]  = c * ai - s * bi;
                    vr[j1] = s * ar + c * br;   vi[j1] = s * ai + c * bi;
                }
            }
            const float ph = w[(d * 4 + i) * 2 + 1];
            const float cp = cosf(0.5f * ph), sp = sinf(0.5f * ph);
#pragma unroll
            for (int j = 0; j < 16; ++j) {
                // bit clear: phase e^{-i ph/2} = (cp, -sp); bit set: (cp, +sp)
                const float pim = (j & mw) ? sp : -sp;
                float ar = vr[j], ai = vi[j];
                vr[j] = cp * ar - pim * ai;
                vi[j] = cp * ai + pim * ar;
            }
        }
    }

#pragma unroll
    for (int j = 0; j < 16; ++j) {
        g_Ur[j * 16 + k] = vr[j];
        g_Ui[j * 16 + k] = vi[j];
    }
}

// ---------------- main: one sample per thread ---------------------------------
__global__ __launch_bounds__(256) void qc_main(const float4* __restrict__ x4,
                                               float4* __restrict__ out4,
                                               int B) {
    const int b = blockIdx.x * blockDim.x + threadIdx.x;
    if (b >= B) return;

    const float4 xv = x4[b];
    const float HPI = 1.57079632679489662f;  // pi/2  (embedding angle/2 = x*pi/2)

    float s0, c0, s1, c1, s2, c2, s3, c3;
    __sincosf(HPI * xv.x, &s0, &c0);
    __sincosf(HPI * xv.y, &s1, &c1);
    __sincosf(HPI * xv.z, &s2, &c2);
    __sincosf(HPI * xv.w, &s3, &c3);

    float p01[4] = { c0 * c1, c0 * s1, s0 * c1, s0 * s1 };
    float p23[4] = { c2 * c3, c2 * s3, s2 * c3, s2 * s3 };

    float e[16];
#pragma unroll
    for (int j = 0; j < 16; ++j) e[j] = p01[j >> 2] * p23[j & 3];

    float o0 = 0.f, o1 = 0.f, o2 = 0.f, o3 = 0.f;
#pragma unroll
    for (int j = 0; j < 16; ++j) {
        float yr = 0.f, yi = 0.f;
#pragma unroll
        for (int k = 0; k < 16; ++k) {
            yr = fmaf(g_Ur[j * 16 + k], e[k], yr);
            yi = fmaf(g_Ui[j * 16 + k], e[k], yi);
        }
        const float p = fmaf(yr, yr, yi * yi);
        o0 = (j & 8) ? o0 - p : o0 + p;
        o1 = (j & 4) ? o1 - p : o1 + p;
        o2 = (j & 2) ? o2 - p : o2 + p;
        o3 = (j & 1) ? o3 - p : o3 + p;
    }

    out4[b] = make_float4(o0, o1, o2, o3);
}

extern "C" void kernel_launch(void* const* d_in, const int* in_sizes, int n_in,
                              void* d_out, int out_size, void* d_ws, size_t ws_size,
                              hipStream_t stream) {
    const float* x = (const float*)d_in[0];
    const float* w = (const float*)d_in[1];
    const int B = in_sizes[0] / 4;  // 1,048,576

    hipLaunchKernelGGL(qc_prep, dim3(1), dim3(64), 0, stream, w);
    hipLaunchKernelGGL(qc_main, dim3((B + 255) / 256), dim3(256), 0, stream,
                       (const float4*)x, (float4*)d_out, B);
}

// Round 2
// 24.974 us; speedup vs baseline: 1.2513x; 1.2513x over previous
//
#include <hip/hip_runtime.h>

// 4-qubit circuit, B=2^20.
// out_w(x) = sum_{a,b in 9x9} K_w[a][b] * F01[a](x0,x1) * F23[b](x2,x3)
// where F01/F23 are outer products of the per-qubit basis {1, cos(pi*x_q), sin(pi*x_q)}
// and K (4x81 floats) depends only on `weights`:
//   psi = U e(x);  out_w = e^T A_w e,  A_w = Re(U^dag Z_w U)  (real symmetric)
//   e_k e_l factorizes per qubit into {c^2, s^2, cs} = {(1+C)/2, (1-C)/2, S/2}.
// Wire w <-> bit (3-w) of flat index j (wire 0 = MSB).

__device__ float g_K[324];  // [w][b][a] : w*81 + b*9 + a;  a = 3*alpha0+alpha1 (qubits 0,1), b = 3*alpha2+alpha3 (qubits 2,3)

// ---------------- prep: weights -> K (one block) ------------------------------
__global__ __launch_bounds__(384) void qc_prep(const float* __restrict__ w) {
    __shared__ float sUr[16][16], sUi[16][16];
    __shared__ float sA[4][16][16];
    const int tid = threadIdx.x;

    // Phase 1: lanes 0..15 build U columns (verified in round 0)
    if (tid < 16) {
        const int k = tid;
        float vr[16], vi[16];
#pragma unroll
        for (int j = 0; j < 16; ++j) { vr[j] = (j == k) ? 1.f : 0.f; vi[j] = 0.f; }
#pragma unroll
        for (int d = 0; d < 2; ++d) {
#pragma unroll
            for (int p = 0; p < 4; ++p) {
                const int mc = 8 >> p;
                const int mt = 8 >> ((p + 1) & 3);
#pragma unroll
                for (int j = 0; j < 16; ++j) {
                    if ((j & mc) && !(j & mt)) {
                        const int j2 = j | mt;
                        float tr = vr[j], ti = vi[j];
                        vr[j] = vr[j2];  vi[j] = vi[j2];
                        vr[j2] = tr;     vi[j2] = ti;
                    }
                }
            }
#pragma unroll
            for (int i = 0; i < 4; ++i) {
                const int mw = 8 >> i;
                const float th = w[(d * 4 + i) * 2 + 0];
                const float c = cosf(0.5f * th), s = sinf(0.5f * th);
#pragma unroll
                for (int j = 0; j < 16; ++j) {
                    if (!(j & mw)) {
                        const int j1 = j | mw;
                        float ar = vr[j], ai = vi[j], br = vr[j1], bi = vi[j1];
                        vr[j]  = c * ar - s * br;   vi[j]  = c * ai - s * bi;
                        vr[j1] = s * ar + c * br;   vi[j1] = s * ai + c * bi;
                    }
                }
                const float ph = w[(d * 4 + i) * 2 + 1];
                const float cp = cosf(0.5f * ph), sp = sinf(0.5f * ph);
#pragma unroll
                for (int j = 0; j < 16; ++j) {
                    const float pim = (j & mw) ? sp : -sp;
                    float ar = vr[j], ai = vi[j];
                    vr[j] = cp * ar - pim * ai;
                    vi[j] = cp * ai + pim * ar;
                }
            }
        }
#pragma unroll
        for (int j = 0; j < 16; ++j) { sUr[j][k] = vr[j]; sUi[j][k] = vi[j]; }
    }
    __syncthreads();

    // Phase 2: A_w[k][l] = sum_j sign_w(j) * (Ur[j][k]Ur[j][l] + Ui[j][k]Ui[j][l])
    if (tid < 256) {
        const int k = tid >> 4, l = tid & 15;
        float g[16];
#pragma unroll
        for (int j = 0; j < 16; ++j)
            g[j] = sUr[j][k] * sUr[j][l] + sUi[j][k] * sUi[j][l];
#pragma unroll
        for (int w4 = 0; w4 < 4; ++w4) {
            float a = 0.f;
#pragma unroll
            for (int j = 0; j < 16; ++j)
                a += ((j >> (3 - w4)) & 1) ? -g[j] : g[j];
            sA[w4][k][l] = a;
        }
    }
    __syncthreads();

    // Phase 3: K[w][a][b] = (1/16) * sum over 16 pair-choices of +/- A_w[k][l]
    // per-qubit map to basis {1, C, S}:
    //   alpha=0: (0,0)+ (1,1)+ ; alpha=1: (0,0)+ (1,1)- ; alpha=2: (0,1)+ (1,0)+
    if (tid < 324) {
        const int w4 = tid / 81, r = tid % 81;
        const int bb = r / 9, aa = r % 9;
        const int al[4] = { aa / 3, aa % 3, bb / 3, bb % 3 };  // alpha per qubit q=0..3
        float acc = 0.f;
#pragma unroll
        for (int t = 0; t < 16; ++t) {
            int k = 0, l = 0;
            float sgn = 1.f;
#pragma unroll
            for (int q = 0; q < 4; ++q) {
                const int alpha = al[q];
                const int c = (t >> q) & 1;
                int bk, bl;
                if (alpha == 2) { bk = c; bl = c ^ 1; }
                else           { bk = c; bl = c; if (alpha == 1 && c) sgn = -sgn; }
                k |= bk << (3 - q);
                l |= bl << (3 - q);
            }
            acc += sgn * sA[w4][k][l];
        }
        g_K[tid] = acc * 0.0625f;  // tid = w4*81 + bb*9 + aa
    }
}

// ---------------- main: 2 samples per thread ----------------------------------
#define COMPUTE_W(W, O0, O1)                                        \
    do {                                                            \
        const float* Kw = g_K + (W) * 81;                           \
        float o0a = 0.f, o1a = 0.f;                                 \
        _Pragma("unroll")                                           \
        for (int b = 0; b < 9; ++b) {                               \
            float t0 = Kw[b * 9];                                   \
            float t1 = t0;                                          \
            _Pragma("unroll")                                       \
            for (int a = 1; a < 9; ++a) {                           \
                const float kv = Kw[b * 9 + a];                     \
                t0 = fmaf(kv, f01a[0][a], t0);                      \
                t1 = fmaf(kv, f01a[1][a], t1);                      \
            }                                                       \
            if (b == 0) { o0a = t0; o1a = t1; }                     \
            else {                                                  \
                o0a = fmaf(t0, f23a[0][b], o0a);                    \
                o1a = fmaf(t1, f23a[1][b], o1a);                    \
            }                                                       \
        }                                                           \
        O0 = o0a; O1 = o1a;                                         \
    } while (0)

__global__ __launch_bounds__(256) void qc_main(const float4* __restrict__ x4,
                                               float4* __restrict__ out4) {
    const int base = blockIdx.x * 512 + threadIdx.x;
    const float PI = 3.14159265358979323846f;

    float f01a[2][9], f23a[2][9];
#pragma unroll
    for (int s = 0; s < 2; ++s) {
        const float4 xv = x4[base + 256 * s];
        float S0, C0, S1, C1, S2, C2, S3, C3;
        __sincosf(PI * xv.x, &S0, &C0);
        __sincosf(PI * xv.y, &S1, &C1);
        __sincosf(PI * xv.z, &S2, &C2);
        __sincosf(PI * xv.w, &S3, &C3);
        f01a[s][0] = 1.f;
        f01a[s][1] = C1;        f01a[s][2] = S1;
        f01a[s][3] = C0;        f01a[s][4] = C0 * C1;  f01a[s][5] = C0 * S1;
        f01a[s][6] = S0;        f01a[s][7] = S0 * C1;  f01a[s][8] = S0 * S1;
        f23a[s][0] = 1.f;
        f23a[s][1] = C3;        f23a[s][2] = S3;
        f23a[s][3] = C2;        f23a[s][4] = C2 * C3;  f23a[s][5] = C2 * S3;
        f23a[s][6] = S2;        f23a[s][7] = S2 * C3;  f23a[s][8] = S2 * S3;
    }

    float o00, o01, o02, o03, o10, o11, o12, o13;
    COMPUTE_W(0, o00, o10);
    COMPUTE_W(1, o01, o11);
    COMPUTE_W(2, o02, o12);
    COMPUTE_W(3, o03, o13);

    out4[base]       = make_float4(o00, o01, o02, o03);
    out4[base + 256] = make_float4(o10, o11, o12, o13);
}

extern "C" void kernel_launch(void* const* d_in, const int* in_sizes, int n_in,
                              void* d_out, int out_size, void* d_ws, size_t ws_size,
                              hipStream_t stream) {
    const float* x = (const float*)d_in[0];
    const float* w = (const float*)d_in[1];
    const int B = in_sizes[0] / 4;  // 1,048,576

    hipLaunchKernelGGL(qc_prep, dim3(1), dim3(384), 0, stream, w);
    hipLaunchKernelGGL(qc_main, dim3(B / 512), dim3(256), 0, stream,
                       (const float4*)x, (float4*)d_out);
}